// Round 11
// baseline (640.932 us; speedup 1.0000x reference)
//
#include <hip/hip_runtime.h>
#include <math.h>

#define N_NODES 50000
#define E_EDGES 800000
#define ETOT    (E_EDGES + N_NODES)   /* 850000 with self loops */
#define HIDF    128
#define HEADS   4
#define CH      32
#define G_GRAPHS 512
#define NEG_SLOPE 0.2f
#define KSLC 32

#define SC_ELEMS  1024
#define SC_BLOCKS ((N_NODES + SC_ELEMS - 1) / SC_ELEMS)   /* 49 */

// ---------- GEMM + fused attention dots ----------
// out[n,128] = A[n,128] @ W[128,128]; also a_src/a_dst[n,4] = per-head dots.
// BM=128, BK=32, 8x8 register tile. A staged k-major (transposed) so each kk
// needs only 4 ds_read_b128 per thread for 64 FMAs (16 FMA/read vs 10.7 before).
// LDS 34 KB -> 4 blocks/CU.
__global__ __launch_bounds__(256) void gemm_att(const float* __restrict__ A,
                                                const float* __restrict__ W,
                                                const float* __restrict__ att_src,
                                                const float* __restrict__ att_dst,
                                                float* __restrict__ out,
                                                float* __restrict__ a_src,
                                                float* __restrict__ a_dst, int n) {
    __shared__ float As[KSLC][133];   // [k][row], padded
    __shared__ float Ws[KSLC][133];   // [k][col], padded
    const int t = threadIdx.x;
    const int row0 = blockIdx.x * 128;

    const int tr = t >> 4;   // 0..15 -> rows tr*8..tr*8+7
    const int tc = t & 15;   // 0..15 -> cols tc*8..tc*8+7

    float acc[8][8];
#pragma unroll
    for (int i = 0; i < 8; i++)
#pragma unroll
        for (int j = 0; j < 8; j++) acc[i][j] = 0.f;

    const float4* W4 = (const float4*)W;
    const float4* A4 = (const float4*)A;

    for (int ks = 0; ks < 128; ks += KSLC) {
        __syncthreads();   // previous slice's readers done
        // stage W slice: W[ks..ks+31][0..127] = 1024 float4, 4/thread
#pragma unroll
        for (int i = 0; i < 4; i++) {
            int idx = t + 256 * i;
            int kk = idx >> 5, c4 = idx & 31;
            *(float4*)&Ws[kk][c4 * 4] = W4[(size_t)(ks + kk) * 32 + c4];
        }
        // stage A slice transposed: A[row0+r][ks..ks+31] -> As[k][r]
#pragma unroll
        for (int i = 0; i < 4; i++) {
            int r  = (t >> 3) + 32 * i;   // 0..127
            int kq = t & 7;               // float4 index within 32-k slice
            float4 v = make_float4(0.f, 0.f, 0.f, 0.f);
            if (row0 + r < n) v = A4[(size_t)(row0 + r) * 32 + (ks >> 2) + kq];
            As[kq * 4 + 0][r] = v.x;
            As[kq * 4 + 1][r] = v.y;
            As[kq * 4 + 2][r] = v.z;
            As[kq * 4 + 3][r] = v.w;
        }
        __syncthreads();

#pragma unroll
        for (int kk = 0; kk < KSLC; kk++) {
            float4 a0 = *(const float4*)&As[kk][tr * 8];
            float4 a1 = *(const float4*)&As[kk][tr * 8 + 4];
            float4 w0 = *(const float4*)&Ws[kk][tc * 8];
            float4 w1 = *(const float4*)&Ws[kk][tc * 8 + 4];
            float av[8] = {a0.x, a0.y, a0.z, a0.w, a1.x, a1.y, a1.z, a1.w};
            float wv[8] = {w0.x, w0.y, w0.z, w0.w, w1.x, w1.y, w1.z, w1.w};
#pragma unroll
            for (int i = 0; i < 8; i++)
#pragma unroll
                for (int j = 0; j < 8; j++) acc[i][j] += av[i] * wv[j];
        }
    }

    // ---- store C tile ----
#pragma unroll
    for (int i = 0; i < 8; i++) {
        int r = row0 + tr * 8 + i;
        if (r < n) {
            float* op = out + (size_t)r * 128 + tc * 8;
            *(float4*)op       = make_float4(acc[i][0], acc[i][1], acc[i][2], acc[i][3]);
            *(float4*)(op + 4) = make_float4(acc[i][4], acc[i][5], acc[i][6], acc[i][7]);
        }
    }

    // ---- fused attention dots: head of this thread's 8 cols = tc>>2 ----
    const int hd = tc >> 2;
    const int jo = hd * CH + (tc & 3) * 8;
    float sv[8], dv[8];
    *(float4*)&sv[0] = *(const float4*)&att_src[jo];
    *(float4*)&sv[4] = *(const float4*)&att_src[jo + 4];
    *(float4*)&dv[0] = *(const float4*)&att_dst[jo];
    *(float4*)&dv[4] = *(const float4*)&att_dst[jo + 4];

    __syncthreads();                 // all reads of As/Ws done; safe to reuse
    float* red2 = &As[0][0];         // layout: red2[row*32 + tc*2 + {0,1}], 4096 floats
#pragma unroll
    for (int i = 0; i < 8; i++) {
        float ps = 0.f, pd = 0.f;
#pragma unroll
        for (int j = 0; j < 8; j++) { ps += acc[i][j] * sv[j]; pd += acc[i][j] * dv[j]; }
        red2[(tr * 8 + i) * 32 + tc * 2]     = ps;
        red2[(tr * 8 + i) * 32 + tc * 2 + 1] = pd;
    }
    __syncthreads();

    // 512 (row,head) pairs; 2 per thread
#pragma unroll
    for (int rr = 0; rr < 2; rr++) {
        int idx = t + 256 * rr;
        int r = idx >> 2, hd2 = idx & 3;
        float ps = 0.f, pd = 0.f;
#pragma unroll
        for (int q = 0; q < 4; q++) {
            ps += red2[r * 32 + (hd2 * 4 + q) * 2];
            pd += red2[r * 32 + (hd2 * 4 + q) * 2 + 1];
        }
        int row = row0 + r;
        if (row < n) {
            a_src[row * 4 + hd2] = ps;
            a_dst[row * 4 + hd2] = pd;
        }
    }
}

// ---------- CSR build: histogram, hierarchical scan, fill ----------
__global__ void hist_k(const int* __restrict__ ei, int* __restrict__ cnt) {
    int e = blockIdx.x * blockDim.x + threadIdx.x;
    if (e >= ETOT) return;
    int d = (e < E_EDGES) ? ei[E_EDGES + e] : e - E_EDGES;
    atomicAdd(&cnt[d], 1);
}

__global__ __launch_bounds__(256) void scan_bsum(const int* __restrict__ cnt,
                                                 int* __restrict__ bsum) {
    int b = blockIdx.x, t = threadIdx.x;
    int base = b * SC_ELEMS + t * 4;
    int s = 0;
#pragma unroll
    for (int q = 0; q < 4; q++) { int idx = base + q; if (idx < N_NODES) s += cnt[idx]; }
    __shared__ int red[256];
    red[t] = s;
    __syncthreads();
    for (int st = 128; st > 0; st >>= 1) {
        if (t < st) red[t] += red[t + st];
        __syncthreads();
    }
    if (t == 0) bsum[b] = red[0];
}

__global__ __launch_bounds__(64) void scan_boff(const int* __restrict__ bsum,
                                                int* __restrict__ boff,
                                                int* __restrict__ rowptr_last) {
    int t = threadIdx.x;
    int v = (t < SC_BLOCKS) ? bsum[t] : 0;
    int incl = v;
#pragma unroll
    for (int off = 1; off < 64; off <<= 1) {
        int u = __shfl_up(incl, off);
        if (t >= off) incl += u;
    }
    if (t < SC_BLOCKS) boff[t] = incl - v;
    if (t == 63) rowptr_last[0] = incl;   // total = rowptr[N_NODES]
}

__global__ __launch_bounds__(256) void scan_write(const int* __restrict__ cnt,
                                                  const int* __restrict__ boff,
                                                  int* __restrict__ rowptr) {
    int b = blockIdx.x, t = threadIdx.x;
    int base = b * SC_ELEMS + t * 4;
    int v[4]; int s = 0;
#pragma unroll
    for (int q = 0; q < 4; q++) { int idx = base + q; v[q] = (idx < N_NODES) ? cnt[idx] : 0; s += v[q]; }
    __shared__ int red[256];
    red[t] = s;
    __syncthreads();
    for (int off = 1; off < 256; off <<= 1) {
        int u = (t >= off) ? red[t - off] : 0;
        __syncthreads();
        red[t] += u;
        __syncthreads();
    }
    int run = boff[b] + red[t] - s;   // exclusive offset for this thread's 4 elems
#pragma unroll
    for (int q = 0; q < 4; q++) {
        int idx = base + q;
        if (idx < N_NODES) rowptr[idx] = run;
        run += v[q];
    }
}

__global__ void fill_k(const int* __restrict__ ei, const int* __restrict__ rowptr,
                       int* __restrict__ cursor, int* __restrict__ col) {
    int e = blockIdx.x * blockDim.x + threadIdx.x;
    if (e >= ETOT) return;
    int s, d;
    if (e < E_EDGES) { s = ei[e]; d = ei[E_EDGES + e]; }
    else             { s = d = e - E_EDGES; }
    int pos = atomicAdd(&cursor[d], 1);
    col[rowptr[d] + pos] = s;
}

// ---------- fused GAT layer: one 64-lane wave per destination node ----------
// R8 structure (best measured: 71.4 us, 24 VGPR, ~76% occupancy).
// 4 edges per inner iteration, 16 lanes (32B channel slice) per edge.
// No max-subtraction: softmax is shift-invariant; |logits| << 88 so exp is safe.
__global__ __launch_bounds__(256) void gat_wave(const float* __restrict__ h,
                                                const float4* __restrict__ a_src4,
                                                const float4* __restrict__ a_dst4,
                                                const int* __restrict__ rowptr,
                                                const int* __restrict__ col,
                                                const float* __restrict__ bias,
                                                float* __restrict__ out) {
    const int wid  = (blockIdx.x * 256 + threadIdx.x) >> 6;   // node id
    const int lane = threadIdx.x & 63;
    if (wid >= N_NODES) return;
    const int beg = rowptr[wid], end = rowptr[wid + 1];
    const float4 ad = a_dst4[wid];
    const int part = lane & 15;      // channel slice: floats part*8 .. part*8+7
    const int egrp = lane >> 4;      // which edge of the quad this lane serves
    const int head = part >> 2;      // head of this channel slice

    float acc[8];
#pragma unroll
    for (int j = 0; j < 8; j++) acc[j] = 0.f;
    float4 den = make_float4(0.f, 0.f, 0.f, 0.f);

    for (int base = beg; base < end; base += 64) {
        int i = base + lane;
        int s = 0;
        float4 ex = make_float4(0.f, 0.f, 0.f, 0.f);
        if (i < end) {
            s = col[i];
            float4 as = a_src4[s];
            float vx = as.x + ad.x, vy = as.y + ad.y, vz = as.z + ad.z, vw = as.w + ad.w;
            vx = vx > 0.f ? vx : NEG_SLOPE * vx;
            vy = vy > 0.f ? vy : NEG_SLOPE * vy;
            vz = vz > 0.f ? vz : NEG_SLOPE * vz;
            vw = vw > 0.f ? vw : NEG_SLOPE * vw;
            ex = make_float4(__expf(vx), __expf(vy), __expf(vz), __expf(vw));
            den.x += ex.x; den.y += ex.y; den.z += ex.z; den.w += ex.w;
        }
        int cnt = end - base; if (cnt > 64) cnt = 64;
        int quads = (cnt + 3) >> 2;
        for (int k = 0; k < quads; k++) {
            int src_lane = 4 * k + egrp;          // invalid lanes hold ex=0,s=0
            int   sk = __shfl(s, src_lane);
            float e0 = __shfl(ex.x, src_lane);
            float e1 = __shfl(ex.y, src_lane);
            float e2 = __shfl(ex.z, src_lane);
            float e3 = __shfl(ex.w, src_lane);
            float aV = head == 0 ? e0 : head == 1 ? e1 : head == 2 ? e2 : e3;
            const float4* hp = (const float4*)(h + (size_t)sk * HIDF + part * 8);
            float4 v0 = hp[0], v1 = hp[1];
            acc[0] += aV * v0.x; acc[1] += aV * v0.y;
            acc[2] += aV * v0.z; acc[3] += aV * v0.w;
            acc[4] += aV * v1.x; acc[5] += aV * v1.y;
            acc[6] += aV * v1.z; acc[7] += aV * v1.w;
        }
    }

    // ---- combine the 4 edge-groups (lanes l, l^16, l^32, l^48 share channels) ----
#pragma unroll
    for (int j = 0; j < 8; j++) {
        acc[j] += __shfl_xor(acc[j], 16);
        acc[j] += __shfl_xor(acc[j], 32);
    }
    // ---- full-wave denominator reduction ----
#pragma unroll
    for (int off = 32; off > 0; off >>= 1) {
        den.x += __shfl_xor(den.x, off);
        den.y += __shfl_xor(den.y, off);
        den.z += __shfl_xor(den.z, off);
        den.w += __shfl_xor(den.w, off);
    }
    float d = head == 0 ? den.x : head == 1 ? den.y : head == 2 ? den.z : den.w;
    float inv = 1.f / d;

    if (lane < 16) {
        const float* bp = bias + part * 8;
        float o[8];
#pragma unroll
        for (int j = 0; j < 8; j++) {
            float v = acc[j] * inv + bp[j];
            o[j] = v > 0.f ? v : expm1f(v);
        }
        float* op = out + (size_t)wid * HIDF + part * 8;
        *(float4*)op       = make_float4(o[0], o[1], o[2], o[3]);
        *(float4*)(op + 4) = make_float4(o[4], o[5], o[6], o[7]);
    }
}

// ---------- graph boundary offsets (batch is sorted) ----------
__global__ void gstart_k(const int* __restrict__ batch, int* __restrict__ gstart) {
    int i = blockIdx.x * blockDim.x + threadIdx.x;
    if (i >= N_NODES) return;
    int b = batch[i];
    int bp = (i == 0) ? -1 : batch[i - 1];
    for (int g = bp + 1; g <= b; g++) gstart[g] = i;
    if (i == N_NODES - 1)
        for (int g = b + 1; g <= G_GRAPHS; g++) gstart[g] = N_NODES;
}

// ---------- fused mean-pool + MLP: one block per graph, no atomics ----------
__global__ __launch_bounds__(128) void pool_mlp(const float* __restrict__ h,
                                                const int* __restrict__ gstart,
                                                const float* __restrict__ W1,
                                                const float* __restrict__ b1,
                                                const float* __restrict__ W2,
                                                const float* __restrict__ b2,
                                                float* __restrict__ out) {
    int g = blockIdx.x, j = threadIdx.x;
    int s = gstart[g], e = gstart[g + 1];
    float acc = 0.f;
    for (int i = s; i < e; i++) acc += h[(size_t)i * HIDF + j];
    float c = (float)(e - s); c = c > 1.f ? c : 1.f;
    __shared__ float gv[128];
    __shared__ float red[128];
    gv[j] = acc / c;
    __syncthreads();
    float a1 = b1[j];
    for (int k = 0; k < 128; k++) a1 += gv[k] * W1[k * 128 + j];
    a1 = a1 > 0.f ? a1 : 0.f;
    red[j] = a1 * W2[j];
    __syncthreads();
    for (int st = 64; st > 0; st >>= 1) {
        if (j < st) red[j] += red[j + st];
        __syncthreads();
    }
    if (j == 0) out[g] = red[0] + b2[0];
}

extern "C" void kernel_launch(void* const* d_in, const int* in_sizes, int n_in,
                              void* d_out, int out_size, void* d_ws, size_t ws_size,
                              hipStream_t stream) {
    const float* x   = (const float*)d_in[0];
    const int* ei    = (const int*)d_in[1];
    const int* batch = (const int*)d_in[3];
    const float* convW[3]  = { (const float*)d_in[4],  (const float*)d_in[8],  (const float*)d_in[12] };
    const float* convAS[3] = { (const float*)d_in[5],  (const float*)d_in[9],  (const float*)d_in[13] };
    const float* convAD[3] = { (const float*)d_in[6],  (const float*)d_in[10], (const float*)d_in[14] };
    const float* convB[3]  = { (const float*)d_in[7],  (const float*)d_in[11], (const float*)d_in[15] };
    const float* mlp_W1 = (const float*)d_in[16];
    const float* mlp_b1 = (const float*)d_in[17];
    const float* mlp_W2 = (const float*)d_in[18];
    const float* mlp_b2 = (const float*)d_in[19];
    float* out = (float*)d_out;

    float* ws = (float*)d_ws;
    float* bufA  = ws;                                           // N*128
    float* bufB  = bufA + (size_t)N_NODES * HIDF;                // N*128
    float* a_src = bufB + (size_t)N_NODES * HIDF;                // N*4
    float* a_dst = a_src + (size_t)N_NODES * HEADS;              // N*4
    int* cnt     = (int*)(a_dst + (size_t)N_NODES * HEADS);      // N
    int* rowptr  = cnt + N_NODES;                                // N+1
    int* col     = rowptr + (N_NODES + 1);                       // ETOT
    int* gstart  = col + ETOT;                                   // G+1
    int* bsum    = gstart + (G_GRAPHS + 1);                      // SC_BLOCKS
    int* boff    = bsum + SC_BLOCKS;                             // SC_BLOCKS

    const int B = 256;
    const int gridGemm = (N_NODES + 127) / 128;
    const int gridEtot = (ETOT + B - 1) / B;
    const int gridWave = (N_NODES * 64 + B - 1) / B;
    const int gridN    = (N_NODES + B - 1) / B;

    // ---- build CSR by destination (topology is layer-invariant) ----
    hipMemsetAsync(cnt, 0, (size_t)N_NODES * sizeof(int), stream);
    hist_k<<<gridEtot, B, 0, stream>>>(ei, cnt);
    scan_bsum<<<SC_BLOCKS, 256, 0, stream>>>(cnt, bsum);
    scan_boff<<<1, 64, 0, stream>>>(bsum, boff, rowptr + N_NODES);
    scan_write<<<SC_BLOCKS, 256, 0, stream>>>(cnt, boff, rowptr);
    hipMemsetAsync(cnt, 0, (size_t)N_NODES * sizeof(int), stream);
    fill_k<<<gridEtot, B, 0, stream>>>(ei, rowptr, cnt, col);
    gstart_k<<<gridN, B, 0, stream>>>(batch, gstart);

    const float* cur = x;
    for (int L = 0; L < 3; L++) {
        gemm_att<<<gridGemm, B, 0, stream>>>(cur, convW[L], convAS[L], convAD[L],
                                             bufA, a_src, a_dst, N_NODES);
        gat_wave<<<gridWave, B, 0, stream>>>(bufA, (const float4*)a_src, (const float4*)a_dst,
                                             rowptr, col, convB[L], bufB);
        cur = bufB;
    }

    pool_mlp<<<G_GRAPHS, 128, 0, stream>>>(bufB, gstart, mlp_W1, mlp_b1, mlp_W2, mlp_b2, out);
}

// Round 12
// 579.528 us; speedup vs baseline: 1.1060x; 1.1060x over previous
//
#include <hip/hip_runtime.h>
#include <math.h>

#define N_NODES 50000
#define E_EDGES 800000
#define ETOT    (E_EDGES + N_NODES)   /* 850000 with self loops */
#define HIDF    128
#define HEADS   4
#define CH      32
#define G_GRAPHS 512
#define NEG_SLOPE 0.2f
#define KSLC 32

#define SC_ELEMS  1024
#define SC_BLOCKS ((N_NODES + SC_ELEMS - 1) / SC_ELEMS)   /* 49 */

// ---------- GEMM + fused attention dots (R8 version: proven fastest) ----------
// out[n,128] = A[n,128] @ W[128,128]; also a_src/a_dst[n,4] = per-head dots.
// W staged in K-slices of 32 -> 50 KB LDS -> 3 blocks/CU.
__global__ __launch_bounds__(256) void gemm_att(const float* __restrict__ A,
                                                const float* __restrict__ W,
                                                const float* __restrict__ att_src,
                                                const float* __restrict__ att_dst,
                                                float* __restrict__ out,
                                                float* __restrict__ a_src,
                                                float* __restrict__ a_dst, int n) {
    __shared__ float Ws[KSLC][128];   // 16 KB, restaged 4x
    __shared__ float As[64][132];     // 33.8 KB (+4 pad); reused as epilogue buffer
    const int t = threadIdx.x;
    const int row0 = blockIdx.x * 64;

    // stage A tile (full K): 64 rows x 128 cols = 2048 float4, 8 per thread
#pragma unroll
    for (int i = 0; i < 8; i++) {
        int idx = t + 256 * i;
        int r = idx >> 5, c4 = idx & 31;
        float4 v = make_float4(0.f, 0.f, 0.f, 0.f);
        if (row0 + r < n) v = ((const float4*)A)[(size_t)(row0 + r) * 32 + c4];
        *(float4*)&As[r][c4 * 4] = v;
    }

    const int tr = t >> 4;   // row group 0..15 (rows tr*4..tr*4+3)
    const int tc = t & 15;   // col group 0..15 (cols tc*8..tc*8+7)
    float acc[4][8];
#pragma unroll
    for (int i = 0; i < 4; i++)
#pragma unroll
        for (int j = 0; j < 8; j++) acc[i][j] = 0.f;

    const float4* W4 = (const float4*)W;
    for (int ks = 0; ks < 128; ks += KSLC) {
        __syncthreads();   // previous slice's readers done (also covers A staging)
        // stage W slice: 32x128 = 1024 float4, 4 per thread
#pragma unroll
        for (int i = 0; i < 4; i++) {
            int idx = t + 256 * i;
            int kk = idx >> 5, c4 = idx & 31;
            *(float4*)&Ws[kk][c4 * 4] = W4[(size_t)(ks + kk) * 32 + c4];
        }
        __syncthreads();

#pragma unroll
        for (int k = 0; k < KSLC; k += 4) {
            float a[4][4];
#pragma unroll
            for (int i = 0; i < 4; i++)
                *(float4*)&a[i][0] = *(const float4*)&As[tr * 4 + i][ks + k];
#pragma unroll
            for (int kk = 0; kk < 4; kk++) {
                float4 w0 = *(const float4*)&Ws[k + kk][tc * 8];
                float4 w1 = *(const float4*)&Ws[k + kk][tc * 8 + 4];
#pragma unroll
                for (int i = 0; i < 4; i++) {
                    float av = a[i][kk];
                    acc[i][0] += av * w0.x; acc[i][1] += av * w0.y;
                    acc[i][2] += av * w0.z; acc[i][3] += av * w0.w;
                    acc[i][4] += av * w1.x; acc[i][5] += av * w1.y;
                    acc[i][6] += av * w1.z; acc[i][7] += av * w1.w;
                }
            }
        }
    }

    // ---- store C tile ----
#pragma unroll
    for (int i = 0; i < 4; i++) {
        int r = row0 + tr * 4 + i;
        if (r < n) {
            float* op = out + (size_t)r * 128 + tc * 8;
            *(float4*)op       = make_float4(acc[i][0], acc[i][1], acc[i][2], acc[i][3]);
            *(float4*)(op + 4) = make_float4(acc[i][4], acc[i][5], acc[i][6], acc[i][7]);
        }
    }

    // ---- fused attention dots: head of this thread's 8 cols = tc>>2 ----
    const int hd = tc >> 2;
    const int jo = hd * CH + (tc & 3) * 8;
    float sv[8], dv[8];
    *(float4*)&sv[0] = *(const float4*)&att_src[jo];
    *(float4*)&sv[4] = *(const float4*)&att_src[jo + 4];
    *(float4*)&dv[0] = *(const float4*)&att_dst[jo];
    *(float4*)&dv[4] = *(const float4*)&att_dst[jo + 4];

    __syncthreads();                 // all reads of As done; safe to reuse
    float* red2 = &As[0][0];         // layout: red2[row*32 + tc*2 + {0,1}]
#pragma unroll
    for (int i = 0; i < 4; i++) {
        float ps = 0.f, pd = 0.f;
#pragma unroll
        for (int j = 0; j < 8; j++) { ps += acc[i][j] * sv[j]; pd += acc[i][j] * dv[j]; }
        red2[(tr * 4 + i) * 32 + tc * 2]     = ps;
        red2[(tr * 4 + i) * 32 + tc * 2 + 1] = pd;
    }
    __syncthreads();

    {   // t -> (row r = t>>2, head hd2 = t&3): reduce over 4 col-threads
        int r = t >> 2, hd2 = t & 3;
        float ps = 0.f, pd = 0.f;
#pragma unroll
        for (int q = 0; q < 4; q++) {
            ps += red2[r * 32 + (hd2 * 4 + q) * 2];
            pd += red2[r * 32 + (hd2 * 4 + q) * 2 + 1];
        }
        int row = row0 + r;
        if (row < n) {
            a_src[row * 4 + hd2] = ps;
            a_dst[row * 4 + hd2] = pd;
        }
    }
}

// ---------- CSR build: histogram, hierarchical scan, fill ----------
__global__ void hist_k(const int* __restrict__ ei, int* __restrict__ cnt) {
    int e = blockIdx.x * blockDim.x + threadIdx.x;
    if (e >= ETOT) return;
    int d = (e < E_EDGES) ? ei[E_EDGES + e] : e - E_EDGES;
    atomicAdd(&cnt[d], 1);
}

__global__ __launch_bounds__(256) void scan_bsum(const int* __restrict__ cnt,
                                                 int* __restrict__ bsum) {
    int b = blockIdx.x, t = threadIdx.x;
    int base = b * SC_ELEMS + t * 4;
    int s = 0;
#pragma unroll
    for (int q = 0; q < 4; q++) { int idx = base + q; if (idx < N_NODES) s += cnt[idx]; }
    __shared__ int red[256];
    red[t] = s;
    __syncthreads();
    for (int st = 128; st > 0; st >>= 1) {
        if (t < st) red[t] += red[t + st];
        __syncthreads();
    }
    if (t == 0) bsum[b] = red[0];
}

__global__ __launch_bounds__(64) void scan_boff(const int* __restrict__ bsum,
                                                int* __restrict__ boff,
                                                int* __restrict__ rowptr_last) {
    int t = threadIdx.x;
    int v = (t < SC_BLOCKS) ? bsum[t] : 0;
    int incl = v;
#pragma unroll
    for (int off = 1; off < 64; off <<= 1) {
        int u = __shfl_up(incl, off);
        if (t >= off) incl += u;
    }
    if (t < SC_BLOCKS) boff[t] = incl - v;
    if (t == 63) rowptr_last[0] = incl;   // total = rowptr[N_NODES]
}

// also zeroes cnt[] after reading (cursor for fill_k) -> saves one memset launch
__global__ __launch_bounds__(256) void scan_write(int* __restrict__ cnt,
                                                  const int* __restrict__ boff,
                                                  int* __restrict__ rowptr) {
    int b = blockIdx.x, t = threadIdx.x;
    int base = b * SC_ELEMS + t * 4;
    int v[4]; int s = 0;
#pragma unroll
    for (int q = 0; q < 4; q++) {
        int idx = base + q;
        v[q] = (idx < N_NODES) ? cnt[idx] : 0; s += v[q];
        if (idx < N_NODES) cnt[idx] = 0;
    }
    __shared__ int red[256];
    red[t] = s;
    __syncthreads();
    for (int off = 1; off < 256; off <<= 1) {
        int u = (t >= off) ? red[t - off] : 0;
        __syncthreads();
        red[t] += u;
        __syncthreads();
    }
    int run = boff[b] + red[t] - s;   // exclusive offset for this thread's 4 elems
#pragma unroll
    for (int q = 0; q < 4; q++) {
        int idx = base + q;
        if (idx < N_NODES) rowptr[idx] = run;
        run += v[q];
    }
}

__global__ void fill_k(const int* __restrict__ ei, const int* __restrict__ rowptr,
                       int* __restrict__ cursor, int* __restrict__ col) {
    int e = blockIdx.x * blockDim.x + threadIdx.x;
    if (e >= ETOT) return;
    int s, d;
    if (e < E_EDGES) { s = ei[e]; d = ei[E_EDGES + e]; }
    else             { s = d = e - E_EDGES; }
    int pos = atomicAdd(&cursor[d], 1);
    col[rowptr[d] + pos] = s;
}

// ---------- fused GAT layer: TWO waves per destination node (channel split) ----
// Wave (node, half) owns 64 channels (heads 2*half, 2*half+1).
// Per edge: 16 lanes x 1 float4 = 256 B gather; 3 shuffles per quad; acc[4].
// Halved per-wave serial chain, 2x wave count -> better latency hiding.
// No max-subtraction: softmax is shift-invariant; |logits| << 88 so exp is safe.
__global__ __launch_bounds__(256) void gat_wave(const float* __restrict__ h,
                                                const float2* __restrict__ a_src2,
                                                const float2* __restrict__ a_dst2,
                                                const int* __restrict__ rowptr,
                                                const int* __restrict__ col,
                                                const float* __restrict__ bias,
                                                float* __restrict__ out) {
    const int gw   = (blockIdx.x * 256 + threadIdx.x) >> 6;   // global wave id
    const int lane = threadIdx.x & 63;
    const int wid  = gw >> 1;          // node id
    const int half = gw & 1;           // channel half: floats half*64 .. half*64+63
    if (wid >= N_NODES) return;
    const int beg = rowptr[wid], end = rowptr[wid + 1];
    const float2 ad = a_dst2[wid * 2 + half];   // my two heads' dst dots
    const int part = lane & 15;        // float4 slice within my half
    const int egrp = lane >> 4;        // which edge of the quad this lane serves
    const int hsel = part >> 3;        // 0/1: which of my two heads

    float acc[4];
#pragma unroll
    for (int j = 0; j < 4; j++) acc[j] = 0.f;
    float2 den = make_float2(0.f, 0.f);

    for (int base = beg; base < end; base += 64) {
        int i = base + lane;
        int s = 0;
        float2 ex = make_float2(0.f, 0.f);
        if (i < end) {
            s = col[i];
            float2 as = a_src2[s * 2 + half];
            float vx = as.x + ad.x, vy = as.y + ad.y;
            vx = vx > 0.f ? vx : NEG_SLOPE * vx;
            vy = vy > 0.f ? vy : NEG_SLOPE * vy;
            ex = make_float2(__expf(vx), __expf(vy));
            den.x += ex.x; den.y += ex.y;
        }
        int cnt = end - base; if (cnt > 64) cnt = 64;
        int quads = (cnt + 3) >> 2;
        for (int k = 0; k < quads; k++) {
            int src_lane = 4 * k + egrp;          // invalid lanes hold ex=0,s=0
            int   sk = __shfl(s, src_lane);
            float e0 = __shfl(ex.x, src_lane);
            float e1 = __shfl(ex.y, src_lane);
            float aV = hsel == 0 ? e0 : e1;
            float4 v = *(const float4*)(h + (size_t)sk * HIDF + half * 64 + part * 4);
            acc[0] += aV * v.x; acc[1] += aV * v.y;
            acc[2] += aV * v.z; acc[3] += aV * v.w;
        }
    }

    // ---- combine the 4 edge-groups (lanes l, l^16, l^32, l^48 share channels) ----
#pragma unroll
    for (int j = 0; j < 4; j++) {
        acc[j] += __shfl_xor(acc[j], 16);
        acc[j] += __shfl_xor(acc[j], 32);
    }
    // ---- full-wave denominator reduction ----
#pragma unroll
    for (int off = 32; off > 0; off >>= 1) {
        den.x += __shfl_xor(den.x, off);
        den.y += __shfl_xor(den.y, off);
    }
    float d = hsel == 0 ? den.x : den.y;
    float inv = 1.f / d;

    if (lane < 16) {
        const float* bp = bias + half * 64 + part * 4;
        float o[4];
#pragma unroll
        for (int j = 0; j < 4; j++) {
            float v = acc[j] * inv + bp[j];
            o[j] = v > 0.f ? v : expm1f(v);
        }
        *(float4*)(out + (size_t)wid * HIDF + half * 64 + part * 4) =
            make_float4(o[0], o[1], o[2], o[3]);
    }
}

// ---------- graph boundary offsets (batch is sorted) ----------
__global__ void gstart_k(const int* __restrict__ batch, int* __restrict__ gstart) {
    int i = blockIdx.x * blockDim.x + threadIdx.x;
    if (i >= N_NODES) return;
    int b = batch[i];
    int bp = (i == 0) ? -1 : batch[i - 1];
    for (int g = bp + 1; g <= b; g++) gstart[g] = i;
    if (i == N_NODES - 1)
        for (int g = b + 1; g <= G_GRAPHS; g++) gstart[g] = N_NODES;
}

// ---------- fused mean-pool + MLP: one block per graph, no atomics ----------
__global__ __launch_bounds__(128) void pool_mlp(const float* __restrict__ h,
                                                const int* __restrict__ gstart,
                                                const float* __restrict__ W1,
                                                const float* __restrict__ b1,
                                                const float* __restrict__ W2,
                                                const float* __restrict__ b2,
                                                float* __restrict__ out) {
    int g = blockIdx.x, j = threadIdx.x;
    int s = gstart[g], e = gstart[g + 1];
    float acc = 0.f;
    for (int i = s; i < e; i++) acc += h[(size_t)i * HIDF + j];
    float c = (float)(e - s); c = c > 1.f ? c : 1.f;
    __shared__ float gv[128];
    __shared__ float red[128];
    gv[j] = acc / c;
    __syncthreads();
    float a1 = b1[j];
    for (int k = 0; k < 128; k++) a1 += gv[k] * W1[k * 128 + j];
    a1 = a1 > 0.f ? a1 : 0.f;
    red[j] = a1 * W2[j];
    __syncthreads();
    for (int st = 64; st > 0; st >>= 1) {
        if (j < st) red[j] += red[j + st];
        __syncthreads();
    }
    if (j == 0) out[g] = red[0] + b2[0];
}

extern "C" void kernel_launch(void* const* d_in, const int* in_sizes, int n_in,
                              void* d_out, int out_size, void* d_ws, size_t ws_size,
                              hipStream_t stream) {
    const float* x   = (const float*)d_in[0];
    const int* ei    = (const int*)d_in[1];
    const int* batch = (const int*)d_in[3];
    const float* convW[3]  = { (const float*)d_in[4],  (const float*)d_in[8],  (const float*)d_in[12] };
    const float* convAS[3] = { (const float*)d_in[5],  (const float*)d_in[9],  (const float*)d_in[13] };
    const float* convAD[3] = { (const float*)d_in[6],  (const float*)d_in[10], (const float*)d_in[14] };
    const float* convB[3]  = { (const float*)d_in[7],  (const float*)d_in[11], (const float*)d_in[15] };
    const float* mlp_W1 = (const float*)d_in[16];
    const float* mlp_b1 = (const float*)d_in[17];
    const float* mlp_W2 = (const float*)d_in[18];
    const float* mlp_b2 = (const float*)d_in[19];
    float* out = (float*)d_out;

    float* ws = (float*)d_ws;
    float* bufA  = ws;                                           // N*128
    float* bufB  = bufA + (size_t)N_NODES * HIDF;                // N*128
    float* a_src = bufB + (size_t)N_NODES * HIDF;                // N*4
    float* a_dst = a_src + (size_t)N_NODES * HEADS;              // N*4
    int* cnt     = (int*)(a_dst + (size_t)N_NODES * HEADS);      // N
    int* rowptr  = cnt + N_NODES;                                // N+1
    int* col     = rowptr + (N_NODES + 1);                       // ETOT
    int* gstart  = col + ETOT;                                   // G+1
    int* bsum    = gstart + (G_GRAPHS + 1);                      // SC_BLOCKS
    int* boff    = bsum + SC_BLOCKS;                             // SC_BLOCKS

    const int B = 256;
    const int gridGemm = (N_NODES + 63) / 64;
    const int gridEtot = (ETOT + B - 1) / B;
    const int gridWave = (N_NODES * 2 * 64 + B - 1) / B;
    const int gridN    = (N_NODES + B - 1) / B;

    // ---- build CSR by destination (topology is layer-invariant) ----
    hipMemsetAsync(cnt, 0, (size_t)N_NODES * sizeof(int), stream);
    hist_k<<<gridEtot, B, 0, stream>>>(ei, cnt);
    scan_bsum<<<SC_BLOCKS, 256, 0, stream>>>(cnt, bsum);
    scan_boff<<<1, 64, 0, stream>>>(bsum, boff, rowptr + N_NODES);
    scan_write<<<SC_BLOCKS, 256, 0, stream>>>(cnt, boff, rowptr);  // also zeroes cnt
    fill_k<<<gridEtot, B, 0, stream>>>(ei, rowptr, cnt, col);
    gstart_k<<<gridN, B, 0, stream>>>(batch, gstart);

    const float* cur = x;
    for (int L = 0; L < 3; L++) {
        gemm_att<<<gridGemm, B, 0, stream>>>(cur, convW[L], convAS[L], convAD[L],
                                             bufA, a_src, a_dst, N_NODES);
        gat_wave<<<gridWave, B, 0, stream>>>(bufA, (const float2*)a_src, (const float2*)a_dst,
                                             rowptr, col, convB[L], bufB);
        cur = bufB;
    }

    pool_mlp<<<G_GRAPHS, 128, 0, stream>>>(bufB, gstart, mlp_W1, mlp_b1, mlp_W2, mlp_b2, out);
}

// Round 13
// 548.483 us; speedup vs baseline: 1.1686x; 1.0566x over previous
//
#include <hip/hip_runtime.h>
#include <math.h>

#define N_NODES 50000
#define E_EDGES 800000
#define ETOT    (E_EDGES + N_NODES)   /* 850000 with self loops */
#define HIDF    128
#define HEADS   4
#define CH      32
#define G_GRAPHS 512
#define NEG_SLOPE 0.2f
#define KSLC 32

#define SC_ELEMS  1024
#define SC_BLOCKS ((N_NODES + SC_ELEMS - 1) / SC_ELEMS)   /* 49 */

// ---------- GEMM + fused attention dots ----------
// out[n,128] = A[n,128] @ W[128,128]; also a_src/a_dst[n,4] = per-head dots.
// BOTH A and W staged per 32-K slice: LDS 25.6 KB -> 6 blocks/CU (24 waves/CU),
// double R8's occupancy; same proven 4x8 register tile and epilogue.
__global__ __launch_bounds__(256) void gemm_att(const float* __restrict__ A,
                                                const float* __restrict__ W,
                                                const float* __restrict__ att_src,
                                                const float* __restrict__ att_dst,
                                                float* __restrict__ out,
                                                float* __restrict__ a_src,
                                                float* __restrict__ a_dst, int n) {
    __shared__ float Ws[KSLC][128];   // 16.4 KB, restaged 4x
    __shared__ float As[64][36];      // 9.2 KB, restaged 4x; epilogue buffer after
    const int t = threadIdx.x;
    const int row0 = blockIdx.x * 64;

    const int tr = t >> 4;   // row group 0..15 (rows tr*4..tr*4+3)
    const int tc = t & 15;   // col group 0..15 (cols tc*8..tc*8+7)
    float acc[4][8];
#pragma unroll
    for (int i = 0; i < 4; i++)
#pragma unroll
        for (int j = 0; j < 8; j++) acc[i][j] = 0.f;

    const float4* W4 = (const float4*)W;
    const float4* A4 = (const float4*)A;

    for (int ks = 0; ks < 128; ks += KSLC) {
        __syncthreads();   // previous slice's readers done
        // stage W slice: 32x128 = 1024 float4, 4 per thread
#pragma unroll
        for (int i = 0; i < 4; i++) {
            int idx = t + 256 * i;
            int kk = idx >> 5, c4 = idx & 31;
            *(float4*)&Ws[kk][c4 * 4] = W4[(size_t)(ks + kk) * 32 + c4];
        }
        // stage A slice: 64 rows x 32 k = 512 float4, 2 per thread
#pragma unroll
        for (int i = 0; i < 2; i++) {
            int idx = t + 256 * i;
            int r = idx >> 3, kq = idx & 7;
            float4 v = make_float4(0.f, 0.f, 0.f, 0.f);
            if (row0 + r < n) v = A4[(size_t)(row0 + r) * 32 + (ks >> 2) + kq];
            *(float4*)&As[r][kq * 4] = v;
        }
        __syncthreads();

#pragma unroll
        for (int k = 0; k < KSLC; k += 4) {
            float a[4][4];
#pragma unroll
            for (int i = 0; i < 4; i++)
                *(float4*)&a[i][0] = *(const float4*)&As[tr * 4 + i][k];
#pragma unroll
            for (int kk = 0; kk < 4; kk++) {
                float4 w0 = *(const float4*)&Ws[k + kk][tc * 8];
                float4 w1 = *(const float4*)&Ws[k + kk][tc * 8 + 4];
#pragma unroll
                for (int i = 0; i < 4; i++) {
                    float av = a[i][kk];
                    acc[i][0] += av * w0.x; acc[i][1] += av * w0.y;
                    acc[i][2] += av * w0.z; acc[i][3] += av * w0.w;
                    acc[i][4] += av * w1.x; acc[i][5] += av * w1.y;
                    acc[i][6] += av * w1.z; acc[i][7] += av * w1.w;
                }
            }
        }
    }

    // ---- store C tile ----
#pragma unroll
    for (int i = 0; i < 4; i++) {
        int r = row0 + tr * 4 + i;
        if (r < n) {
            float* op = out + (size_t)r * 128 + tc * 8;
            *(float4*)op       = make_float4(acc[i][0], acc[i][1], acc[i][2], acc[i][3]);
            *(float4*)(op + 4) = make_float4(acc[i][4], acc[i][5], acc[i][6], acc[i][7]);
        }
    }

    // ---- fused attention dots: head of this thread's 8 cols = tc>>2 ----
    const int hd = tc >> 2;
    const int jo = hd * CH + (tc & 3) * 8;
    float sv[8], dv[8];
    *(float4*)&sv[0] = *(const float4*)&att_src[jo];
    *(float4*)&sv[4] = *(const float4*)&att_src[jo + 4];
    *(float4*)&dv[0] = *(const float4*)&att_dst[jo];
    *(float4*)&dv[4] = *(const float4*)&att_dst[jo + 4];

    __syncthreads();                 // all reads of As done; safe to reuse
    float* red2 = &As[0][0];         // layout: red2[row*32 + tc*2 + {0,1}], 2048 floats
#pragma unroll
    for (int i = 0; i < 4; i++) {
        float ps = 0.f, pd = 0.f;
#pragma unroll
        for (int j = 0; j < 8; j++) { ps += acc[i][j] * sv[j]; pd += acc[i][j] * dv[j]; }
        red2[(tr * 4 + i) * 32 + tc * 2]     = ps;
        red2[(tr * 4 + i) * 32 + tc * 2 + 1] = pd;
    }
    __syncthreads();

    {   // t -> (row r = t>>2, head hd2 = t&3): reduce over 4 col-threads
        int r = t >> 2, hd2 = t & 3;
        float ps = 0.f, pd = 0.f;
#pragma unroll
        for (int q = 0; q < 4; q++) {
            ps += red2[r * 32 + (hd2 * 4 + q) * 2];
            pd += red2[r * 32 + (hd2 * 4 + q) * 2 + 1];
        }
        int row = row0 + r;
        if (row < n) {
            a_src[row * 4 + hd2] = ps;
            a_dst[row * 4 + hd2] = pd;
        }
    }
}

// ---------- CSR build: histogram, hierarchical scan, fill ----------
__global__ void hist_k(const int* __restrict__ ei, int* __restrict__ cnt) {
    int e = blockIdx.x * blockDim.x + threadIdx.x;
    if (e >= ETOT) return;
    int d = (e < E_EDGES) ? ei[E_EDGES + e] : e - E_EDGES;
    atomicAdd(&cnt[d], 1);
}

__global__ __launch_bounds__(256) void scan_bsum(const int* __restrict__ cnt,
                                                 int* __restrict__ bsum) {
    int b = blockIdx.x, t = threadIdx.x;
    int base = b * SC_ELEMS + t * 4;
    int s = 0;
#pragma unroll
    for (int q = 0; q < 4; q++) { int idx = base + q; if (idx < N_NODES) s += cnt[idx]; }
    __shared__ int red[256];
    red[t] = s;
    __syncthreads();
    for (int st = 128; st > 0; st >>= 1) {
        if (t < st) red[t] += red[t + st];
        __syncthreads();
    }
    if (t == 0) bsum[b] = red[0];
}

__global__ __launch_bounds__(64) void scan_boff(const int* __restrict__ bsum,
                                                int* __restrict__ boff,
                                                int* __restrict__ rowptr_last) {
    int t = threadIdx.x;
    int v = (t < SC_BLOCKS) ? bsum[t] : 0;
    int incl = v;
#pragma unroll
    for (int off = 1; off < 64; off <<= 1) {
        int u = __shfl_up(incl, off);
        if (t >= off) incl += u;
    }
    if (t < SC_BLOCKS) boff[t] = incl - v;
    if (t == 63) rowptr_last[0] = incl;   // total = rowptr[N_NODES]
}

// also zeroes cnt[] after reading (cursor for fill_k) -> saves one memset launch
__global__ __launch_bounds__(256) void scan_write(int* __restrict__ cnt,
                                                  const int* __restrict__ boff,
                                                  int* __restrict__ rowptr) {
    int b = blockIdx.x, t = threadIdx.x;
    int base = b * SC_ELEMS + t * 4;
    int v[4]; int s = 0;
#pragma unroll
    for (int q = 0; q < 4; q++) {
        int idx = base + q;
        v[q] = (idx < N_NODES) ? cnt[idx] : 0; s += v[q];
        if (idx < N_NODES) cnt[idx] = 0;
    }
    __shared__ int red[256];
    red[t] = s;
    __syncthreads();
    for (int off = 1; off < 256; off <<= 1) {
        int u = (t >= off) ? red[t - off] : 0;
        __syncthreads();
        red[t] += u;
        __syncthreads();
    }
    int run = boff[b] + red[t] - s;   // exclusive offset for this thread's 4 elems
#pragma unroll
    for (int q = 0; q < 4; q++) {
        int idx = base + q;
        if (idx < N_NODES) rowptr[idx] = run;
        run += v[q];
    }
}

__global__ void fill_k(const int* __restrict__ ei, const int* __restrict__ rowptr,
                       int* __restrict__ cursor, int* __restrict__ col) {
    int e = blockIdx.x * blockDim.x + threadIdx.x;
    if (e >= ETOT) return;
    int s, d;
    if (e < E_EDGES) { s = ei[e]; d = ei[E_EDGES + e]; }
    else             { s = d = e - E_EDGES; }
    int pos = atomicAdd(&cursor[d], 1);
    col[rowptr[d] + pos] = s;
}

// ---------- fused GAT layer: one 64-lane wave per destination node ----------
// FROZEN at the R6/R8 structure: best measured 71.4 us, 24 VGPR, ~76% occupancy.
// Six restructurings (ILP unroll, LDS staging, zero-shuffle, wave-split) all
// regressed -> this is the local optimum for the random 512B gather.
// No max-subtraction: softmax is shift-invariant; |logits| << 88 so exp is safe.
__global__ __launch_bounds__(256) void gat_wave(const float* __restrict__ h,
                                                const float4* __restrict__ a_src4,
                                                const float4* __restrict__ a_dst4,
                                                const int* __restrict__ rowptr,
                                                const int* __restrict__ col,
                                                const float* __restrict__ bias,
                                                float* __restrict__ out) {
    const int wid  = (blockIdx.x * 256 + threadIdx.x) >> 6;   // node id
    const int lane = threadIdx.x & 63;
    if (wid >= N_NODES) return;
    const int beg = rowptr[wid], end = rowptr[wid + 1];
    const float4 ad = a_dst4[wid];
    const int part = lane & 15;      // channel slice: floats part*8 .. part*8+7
    const int egrp = lane >> 4;      // which edge of the quad this lane serves
    const int head = part >> 2;      // head of this channel slice

    float acc[8];
#pragma unroll
    for (int j = 0; j < 8; j++) acc[j] = 0.f;
    float4 den = make_float4(0.f, 0.f, 0.f, 0.f);

    for (int base = beg; base < end; base += 64) {
        int i = base + lane;
        int s = 0;
        float4 ex = make_float4(0.f, 0.f, 0.f, 0.f);
        if (i < end) {
            s = col[i];
            float4 as = a_src4[s];
            float vx = as.x + ad.x, vy = as.y + ad.y, vz = as.z + ad.z, vw = as.w + ad.w;
            vx = vx > 0.f ? vx : NEG_SLOPE * vx;
            vy = vy > 0.f ? vy : NEG_SLOPE * vy;
            vz = vz > 0.f ? vz : NEG_SLOPE * vz;
            vw = vw > 0.f ? vw : NEG_SLOPE * vw;
            ex = make_float4(__expf(vx), __expf(vy), __expf(vz), __expf(vw));
            den.x += ex.x; den.y += ex.y; den.z += ex.z; den.w += ex.w;
        }
        int cnt = end - base; if (cnt > 64) cnt = 64;
        int quads = (cnt + 3) >> 2;
        for (int k = 0; k < quads; k++) {
            int src_lane = 4 * k + egrp;          // invalid lanes hold ex=0,s=0
            int   sk = __shfl(s, src_lane);
            float e0 = __shfl(ex.x, src_lane);
            float e1 = __shfl(ex.y, src_lane);
            float e2 = __shfl(ex.z, src_lane);
            float e3 = __shfl(ex.w, src_lane);
            float aV = head == 0 ? e0 : head == 1 ? e1 : head == 2 ? e2 : e3;
            const float4* hp = (const float4*)(h + (size_t)sk * HIDF + part * 8);
            float4 v0 = hp[0], v1 = hp[1];
            acc[0] += aV * v0.x; acc[1] += aV * v0.y;
            acc[2] += aV * v0.z; acc[3] += aV * v0.w;
            acc[4] += aV * v1.x; acc[5] += aV * v1.y;
            acc[6] += aV * v1.z; acc[7] += aV * v1.w;
        }
    }

    // ---- combine the 4 edge-groups (lanes l, l^16, l^32, l^48 share channels) ----
#pragma unroll
    for (int j = 0; j < 8; j++) {
        acc[j] += __shfl_xor(acc[j], 16);
        acc[j] += __shfl_xor(acc[j], 32);
    }
    // ---- full-wave denominator reduction ----
#pragma unroll
    for (int off = 32; off > 0; off >>= 1) {
        den.x += __shfl_xor(den.x, off);
        den.y += __shfl_xor(den.y, off);
        den.z += __shfl_xor(den.z, off);
        den.w += __shfl_xor(den.w, off);
    }
    float d = head == 0 ? den.x : head == 1 ? den.y : head == 2 ? den.z : den.w;
    float inv = 1.f / d;

    if (lane < 16) {
        const float* bp = bias + part * 8;
        float o[8];
#pragma unroll
        for (int j = 0; j < 8; j++) {
            float v = acc[j] * inv + bp[j];
            o[j] = v > 0.f ? v : expm1f(v);
        }
        float* op = out + (size_t)wid * HIDF + part * 8;
        *(float4*)op       = make_float4(o[0], o[1], o[2], o[3]);
        *(float4*)(op + 4) = make_float4(o[4], o[5], o[6], o[7]);
    }
}

// ---------- graph boundary offsets (batch is sorted) ----------
__global__ void gstart_k(const int* __restrict__ batch, int* __restrict__ gstart) {
    int i = blockIdx.x * blockDim.x + threadIdx.x;
    if (i >= N_NODES) return;
    int b = batch[i];
    int bp = (i == 0) ? -1 : batch[i - 1];
    for (int g = bp + 1; g <= b; g++) gstart[g] = i;
    if (i == N_NODES - 1)
        for (int g = b + 1; g <= G_GRAPHS; g++) gstart[g] = N_NODES;
}

// ---------- fused mean-pool + MLP: one block per graph, no atomics ----------
__global__ __launch_bounds__(128) void pool_mlp(const float* __restrict__ h,
                                                const int* __restrict__ gstart,
                                                const float* __restrict__ W1,
                                                const float* __restrict__ b1,
                                                const float* __restrict__ W2,
                                                const float* __restrict__ b2,
                                                float* __restrict__ out) {
    int g = blockIdx.x, j = threadIdx.x;
    int s = gstart[g], e = gstart[g + 1];
    float acc = 0.f;
    for (int i = s; i < e; i++) acc += h[(size_t)i * HIDF + j];
    float c = (float)(e - s); c = c > 1.f ? c : 1.f;
    __shared__ float gv[128];
    __shared__ float red[128];
    gv[j] = acc / c;
    __syncthreads();
    float a1 = b1[j];
    for (int k = 0; k < 128; k++) a1 += gv[k] * W1[k * 128 + j];
    a1 = a1 > 0.f ? a1 : 0.f;
    red[j] = a1 * W2[j];
    __syncthreads();
    for (int st = 64; st > 0; st >>= 1) {
        if (j < st) red[j] += red[j + st];
        __syncthreads();
    }
    if (j == 0) out[g] = red[0] + b2[0];
}

extern "C" void kernel_launch(void* const* d_in, const int* in_sizes, int n_in,
                              void* d_out, int out_size, void* d_ws, size_t ws_size,
                              hipStream_t stream) {
    const float* x   = (const float*)d_in[0];
    const int* ei    = (const int*)d_in[1];
    const int* batch = (const int*)d_in[3];
    const float* convW[3]  = { (const float*)d_in[4],  (const float*)d_in[8],  (const float*)d_in[12] };
    const float* convAS[3] = { (const float*)d_in[5],  (const float*)d_in[9],  (const float*)d_in[13] };
    const float* convAD[3] = { (const float*)d_in[6],  (const float*)d_in[10], (const float*)d_in[14] };
    const float* convB[3]  = { (const float*)d_in[7],  (const float*)d_in[11], (const float*)d_in[15] };
    const float* mlp_W1 = (const float*)d_in[16];
    const float* mlp_b1 = (const float*)d_in[17];
    const float* mlp_W2 = (const float*)d_in[18];
    const float* mlp_b2 = (const float*)d_in[19];
    float* out = (float*)d_out;

    float* ws = (float*)d_ws;
    float* bufA  = ws;                                           // N*128
    float* bufB  = bufA + (size_t)N_NODES * HIDF;                // N*128
    float* a_src = bufB + (size_t)N_NODES * HIDF;                // N*4
    float* a_dst = a_src + (size_t)N_NODES * HEADS;              // N*4
    int* cnt     = (int*)(a_dst + (size_t)N_NODES * HEADS);      // N
    int* rowptr  = cnt + N_NODES;                                // N+1
    int* col     = rowptr + (N_NODES + 1);                       // ETOT
    int* gstart  = col + ETOT;                                   // G+1
    int* bsum    = gstart + (G_GRAPHS + 1);                      // SC_BLOCKS
    int* boff    = bsum + SC_BLOCKS;                             // SC_BLOCKS

    const int B = 256;
    const int gridGemm = (N_NODES + 63) / 64;
    const int gridEtot = (ETOT + B - 1) / B;
    const int gridWave = (N_NODES * 64 + B - 1) / B;
    const int gridN    = (N_NODES + B - 1) / B;

    // ---- build CSR by destination (topology is layer-invariant) ----
    hipMemsetAsync(cnt, 0, (size_t)N_NODES * sizeof(int), stream);
    hist_k<<<gridEtot, B, 0, stream>>>(ei, cnt);
    scan_bsum<<<SC_BLOCKS, 256, 0, stream>>>(cnt, bsum);
    scan_boff<<<1, 64, 0, stream>>>(bsum, boff, rowptr + N_NODES);
    scan_write<<<SC_BLOCKS, 256, 0, stream>>>(cnt, boff, rowptr);  // also zeroes cnt
    fill_k<<<gridEtot, B, 0, stream>>>(ei, rowptr, cnt, col);
    gstart_k<<<gridN, B, 0, stream>>>(batch, gstart);

    const float* cur = x;
    for (int L = 0; L < 3; L++) {
        gemm_att<<<gridGemm, B, 0, stream>>>(cur, convW[L], convAS[L], convAD[L],
                                             bufA, a_src, a_dst, N_NODES);
        gat_wave<<<gridWave, B, 0, stream>>>(bufA, (const float4*)a_src, (const float4*)a_dst,
                                             rowptr, col, convB[L], bufB);
        cur = bufB;
    }

    pool_mlp<<<G_GRAPHS, 128, 0, stream>>>(bufB, gstart, mlp_W1, mlp_b1, mlp_W2, mlp_b2, out);
}